// Round 7
// baseline (1465.795 us; speedup 1.0000x reference)
//
#include <hip/hip_runtime.h>
#include <hip/hip_bf16.h>

#define NN 50000
#define NE 800000
#define DIMX 288
#define NPB 16   // nodes per block in k_linear1 / k_gate
#define NCNT 50048

typedef float float4v __attribute__((ext_vector_type(4)));
typedef short short8 __attribute__((ext_vector_type(8)));

__device__ __forceinline__ float b2f(unsigned short u) {
  return __uint_as_float(((unsigned int)u) << 16);
}
__device__ __forceinline__ unsigned short f2b(float f) {
  unsigned int x = __float_as_uint(f);
  x += 0x7fffu + ((x >> 16) & 1u);
  return (unsigned short)(x >> 16);
}
__device__ __forceinline__ float ldf(const void* p, long i, int f32) {
  return f32 ? ((const float*)p)[i] : b2f(((const unsigned short*)p)[i]);
}
__device__ __forceinline__ int ldidx(const int* p, long i, int i64) {
  return i64 ? p[2 * i] : p[i];
}

// ---------------- Kernel 0: dtype detector ----------------
__global__ void k_detect(const unsigned short* __restrict__ pos_u16,
                         const int* __restrict__ eidx_i32,
                         int* __restrict__ flags) {
  if (threadIdx.x == 0 && blockIdx.x == 0) {
    int insane = 0;
    for (int i = 0; i < 128; ++i) {
      unsigned short u = pos_u16[i];
      int e = (u >> 7) & 0xff;
      if (e >= 0xC2) insane++;          // |x| >= 2^67 impossible for bf16 pos in [0,10]
    }
    flags[0] = (insane >= 2) ? 1 : 0;
    int nz = 0;
    for (int i = 1; i < 16; i += 2) nz += (eidx_i32[i] != 0);
    flags[1] = (nz == 0) ? 1 : 0;       // int64 high words all zero
  }
}

// ---------------- Kernel 1: si1 = irreps_linear(nodes) -> bf16 ----------------
__global__ __launch_bounds__(256) void k_linear1(
    const void* __restrict__ nodes,
    const void* __restrict__ W0,
    const void* __restrict__ W1,
    const void* __restrict__ W2,
    unsigned short* __restrict__ si1,
    const int* __restrict__ flags) {
  const int f32 = flags[0];
  __shared__ float Ws[3072];
  __shared__ float xs[NPB * DIMX];
  int tid = threadIdx.x;
  for (int idx = tid; idx < 3072; idx += 256) {
    int l = idx >> 10, rem = idx & 1023;
    const void* w = (l == 0) ? W0 : ((l == 1) ? W1 : W2);
    Ws[idx] = ldf(w, rem, f32);
  }
  long base = (long)blockIdx.x * NPB;
  for (int idx = tid; idx < NPB * DIMX; idx += 256)
    xs[idx] = ldf(nodes, base * DIMX + idx, f32);
  __syncthreads();
  int wid = tid >> 6, lane = tid & 63;
  #pragma unroll 1
  for (int t = 0; t < 4; ++t) {
    int nl = wid * 4 + t;
    long node = base + nl;
    const float* x = xs + nl * DIMX;
    #pragma unroll
    for (int r = 0; r < 5; ++r) {
      int j = r * 64 + lane;
      if (j < DIMX) {
        float acc = 0.f;
        if (j < 32) {
          #pragma unroll
          for (int i = 0; i < 32; ++i) acc += x[i] * Ws[i * 32 + j];
        } else if (j < 128) {
          unsigned jj = j - 32; int m = jj / 3u, c = jj % 3u;
          #pragma unroll
          for (int i = 0; i < 32; ++i) acc += x[32 + 3 * i + c] * Ws[1024 + i * 32 + m];
        } else {
          unsigned jj = j - 128; int m = jj / 5u, c = jj % 5u;
          #pragma unroll
          for (int i = 0; i < 32; ++i) acc += x[128 + 5 * i + c] * Ws[2048 + i * 32 + m];
        }
        si1[node * DIMX + j] = f2b(acc);
      }
    }
  }
}

// ---------------- Kernel 2: zero conv ----------------
__global__ __launch_bounds__(256) void k_zero(float* __restrict__ conv) {
  long idx = (long)blockIdx.x * 256 + threadIdx.x;
  if (idx < (long)NN * DIMX / 4) {
    float4 z; z.x = 0.f; z.y = 0.f; z.z = 0.f; z.w = 0.f;
    ((float4*)conv)[idx] = z;
  }
}

// ---------------- Kernel 2b: zero counters ----------------
__global__ __launch_bounds__(256) void k_zcnt(int* __restrict__ cnt) {
  int idx = blockIdx.x * 256 + threadIdx.x;
  if (idx < NCNT) cnt[idx] = 0;
}

// ---------------- Kernel S1: count dst degrees ----------------
__global__ __launch_bounds__(256) void k_count(
    const int* __restrict__ eidx, int* __restrict__ cnt,
    const int* __restrict__ flags) {
  const int i64 = flags[1];
  long e = (long)blockIdx.x * 256 + threadIdx.x;
  if (e < NE) {
    int d = ldidx(eidx, NE + e, i64);
    atomicAdd(&cnt[d], 1);
  }
}

// ---------------- Kernel S2: prefix scan (single block) -> cursors ----------------
__global__ __launch_bounds__(1024) void k_scan(
    const int* __restrict__ cnt, int* __restrict__ cur) {
  __shared__ int part[1024];
  __shared__ int pre[1024];
  int t = threadIdx.x;
  const int CH = 49;  // 1024*49 >= 50000
  int s = 0;
  for (int i = 0; i < CH; ++i) {
    int idx = t * CH + i;
    if (idx < NN) s += cnt[idx];
  }
  part[t] = s;
  __syncthreads();
  if (t == 0) {
    int a = 0;
    for (int i = 0; i < 1024; ++i) { pre[i] = a; a += part[i]; }
  }
  __syncthreads();
  int a = pre[t];
  for (int i = 0; i < CH; ++i) {
    int idx = t * CH + i;
    if (idx < NN) { cur[idx] = a; a += cnt[idx]; }
  }
}

// ---------------- Kernel S3: fill dst-sorted src/dst arrays ----------------
__global__ __launch_bounds__(256) void k_fill(
    const int* __restrict__ eidx, int* __restrict__ cur,
    int* __restrict__ src_s, int* __restrict__ dst_s,
    const int* __restrict__ flags) {
  const int i64 = flags[1];
  long e = (long)blockIdx.x * 256 + threadIdx.x;
  if (e < NE) {
    int s = ldidx(eidx, e, i64);
    int d = ldidx(eidx, NE + e, i64);
    int p = atomicAdd(&cur[d], 1);
    src_s[p] = s;
    dst_s[p] = d;
  }
}

// ---------------- Kernel 3: dst-grouped conv (MFMA radial, register accumulation) ----------------
// block=256 = 4 waves; each wave owns 64 dst-sorted edges (4 MFMA chunks of 16).
// Messages accumulate in registers across same-dst runs; flush per segment (~5/wave)
// with atomicAdd (handles cross-wave boundary dsts).
__global__ __launch_bounds__(256) void k_conv(
    const void* __restrict__ pos,
    const void* __restrict__ Wr1,
    const void* __restrict__ br1,
    const void* __restrict__ Wr2,
    const int* __restrict__ src_s,
    const int* __restrict__ dst_s,
    const unsigned short* __restrict__ si1,
    float* __restrict__ conv,
    const int* __restrict__ flags) {
  const int f32 = flags[0];
  __shared__ unsigned short wr2t[224 * 72];            // [j][k] bf16, pad 64->72
  __shared__ float wr1s[576];                          // Wr1 [8][64] + br1 [64]
  __shared__ int msrc[4][64];
  __shared__ int mdst[4][64];
  __shared__ float cgeom[4][16][17];                   // per-chunk geometry
  __shared__ float wev[4][228];                        // per-wave current-edge w
  __shared__ __align__(16) unsigned short xrows[4][8][296];  // per-wave gathered x (sub-batch)
  int tid = threadIdx.x, lane = tid & 63, wid = tid >> 6;

  for (int idx = tid; idx < 512; idx += 256) wr1s[idx] = ldf(Wr1, idx, f32);
  if (tid < 64) wr1s[512 + tid] = ldf(br1, tid, f32);
  for (int idx = tid; idx < 64 * 224; idx += 256) {
    int k = idx / 224, j = idx - k * 224;
    wr2t[j * 72 + k] = f2b(ldf(Wr2, idx, f32));
  }
  {
    long base = (long)blockIdx.x * 256 + wid * 64;
    msrc[wid][lane] = src_s[base + lane];
    mdst[wid][lane] = dst_s[base + lane];
  }
  __syncthreads();

  const int q = lane >> 4, colA = lane & 15;
  float accr[5] = {0.f, 0.f, 0.f, 0.f, 0.f};
  int cur_dst = mdst[wid][0];

  #pragma unroll 1
  for (int c = 0; c < 4; ++c) {
    // --- geometry for this chunk's 16 edges (lanes 0..15) ---
    if (lane < 16) {
      int s = msrc[wid][c * 16 + lane];
      int d = mdst[wid][c * 16 + lane];
      float rx = ldf(pos, 3 * (long)s, f32)     - ldf(pos, 3 * (long)d, f32);
      float ry = ldf(pos, 3 * (long)s + 1, f32) - ldf(pos, 3 * (long)d + 1, f32);
      float rz = ldf(pos, 3 * (long)s + 2, f32) - ldf(pos, 3 * (long)d + 2, f32);
      float dd = sqrtf(rx * rx + ry * ry + rz * rz + 1e-12f);
      float inv = 1.0f / dd;
      float ux = rx * inv, uy = ry * inv, uz = rz * inv;
      float* G = cgeom[wid][lane];
      G[0] = ux; G[1] = uy; G[2] = uz;
      G[3] = ux * uy;
      G[4] = uy * uz;
      G[5] = (3.f * uz * uz - 1.f) * 0.28867513459481287f;
      G[6] = ux * uz;
      G[7] = (ux * ux - uy * uy) * 0.5f;
      #pragma unroll
      for (int k = 0; k < 8; ++k) {
        float t = dd - (float)k * (5.0f / 7.0f);
        G[8 + k] = __expf(-t * t);
      }
    }
    asm volatile("" ::: "memory");

    // --- h (0.25 = 1/sqrt(AVG_DEG) folded) into A-fragments ---
    short8 afrag0, afrag1;
    {
      const float* rb = &cgeom[wid][colA][8];
      #pragma unroll
      for (int i = 0; i < 8; ++i) {
        int k = q * 8 + i;
        float a = wr1s[512 + k];
        #pragma unroll
        for (int r = 0; r < 8; ++r) a += rb[r] * wr1s[r * 64 + k];
        afrag0[i] = (short)f2b(0.25f * a / (1.f + __expf(-a)));
        int k2 = 32 + q * 8 + i;
        float a2 = wr1s[512 + k2];
        #pragma unroll
        for (int r = 0; r < 8; ++r) a2 += rb[r] * wr1s[r * 64 + k2];
        afrag1[i] = (short)f2b(0.25f * a2 / (1.f + __expf(-a2)));
      }
    }

    // --- 28 MFMA: w for chunk's 16 edges ---
    float4v acc[14];
    #pragma unroll
    for (int t = 0; t < 14; ++t) {
      int j = t * 16 + colA;
      short8 b0 = *(const short8*)&wr2t[j * 72 + q * 8];
      short8 b1 = *(const short8*)&wr2t[j * 72 + 32 + q * 8];
      float4v cc = {0.f, 0.f, 0.f, 0.f};
      cc = __builtin_amdgcn_mfma_f32_16x16x32_bf16(afrag0, b0, cc, 0, 0, 0);
      cc = __builtin_amdgcn_mfma_f32_16x16x32_bf16(afrag1, b1, cc, 0, 0, 0);
      acc[t] = cc;
    }

    #pragma unroll
    for (int sb = 0; sb < 2; ++sb) {
      // --- gather 8 source rows (batched, b128) ---
      if (lane < 36) {
        uint4 t[8];
        #pragma unroll
        for (int e = 0; e < 8; ++e) {
          unsigned s = (unsigned)msrc[wid][c * 16 + sb * 8 + e];
          t[e] = ((const uint4*)(si1 + (size_t)s * DIMX))[lane];
        }
        #pragma unroll
        for (int e = 0; e < 8; ++e)
          ((uint4*)&xrows[wid][e][0])[lane] = t[e];
      }
      asm volatile("" ::: "memory");

      #pragma unroll
      for (int i = 0; i < 8; ++i) {
        const int m = sb * 8 + i;       // edge within chunk (compile-time)
        const int eb = c * 16 + m;      // edge within wave run
        // broadcast w for edge m via LDS
        if (q == (m >> 2)) {
          #pragma unroll
          for (int t = 0; t < 14; ++t) wev[wid][t * 16 + colA] = acc[t][m & 3];
        }
        asm volatile("" ::: "memory");
        int d_e = mdst[wid][eb];
        if (d_e != cur_dst) {           // wave-uniform: flush segment
          float* cv = conv + (size_t)cur_dst * DIMX;
          #pragma unroll
          for (int r = 0; r < 5; ++r) {
            int j = r * 64 + lane;
            if (j < DIMX) { atomicAdd(cv + j, accr[r]); accr[r] = 0.f; }
          }
          cur_dst = d_e;
        }
        // message for edge m -> accumulate in registers
        {
          const float* G = cgeom[wid][m];
          float y1x = G[0], y1y = G[1], y1z = G[2];
          float y20 = G[3], y21 = G[4], y22 = G[5], y23 = G[6], y24 = G[7];
          const unsigned short* X = xrows[wid][i];
          const float* W = wev[wid];
          #pragma unroll
          for (int r = 0; r < 5; ++r) {
            int j = r * 64 + lane;
            if (j < DIMX) {
              float val;
              if (j < 32) {
                int mm = j;
                float d1 = b2f(X[32 + 3 * mm]) * y1x + b2f(X[33 + 3 * mm]) * y1y + b2f(X[34 + 3 * mm]) * y1z;
                float d2 = b2f(X[128 + 5 * mm]) * y20 + b2f(X[129 + 5 * mm]) * y21 + b2f(X[130 + 5 * mm]) * y22
                         + b2f(X[131 + 5 * mm]) * y23 + b2f(X[132 + 5 * mm]) * y24;
                val = W[mm] * b2f(X[mm]) + W[128 + mm] * d1 + W[192 + mm] * d2;
              } else if (j < 128) {
                unsigned jj = j - 32; int mm = jj / 3u, cc = jj % 3u;
                float Yc = (cc == 0) ? y1x : ((cc == 1) ? y1y : y1z);
                val = W[32 + mm] * b2f(X[j]) + W[96 + mm] * b2f(X[mm]) * Yc;
              } else {
                unsigned jj = j - 128; int mm = jj / 5u, cc = jj % 5u;
                float Yc = (cc == 0) ? y20 : (cc == 1) ? y21 : (cc == 2) ? y22 : (cc == 3) ? y23 : y24;
                val = W[64 + mm] * b2f(X[j]) + W[160 + mm] * b2f(X[mm]) * Yc;
              }
              accr[r] += val;
            }
          }
        }
        asm volatile("" ::: "memory");
      }
    }
  }
  // final segment flush
  {
    float* cv = conv + (size_t)cur_dst * DIMX;
    #pragma unroll
    for (int r = 0; r < 5; ++r) {
      int j = r * 64 + lane;
      if (j < DIMX) atomicAdd(cv + j, accr[r]);
    }
  }
}

// ---------------- Kernel 4: si2 = linear(conv); mixed = nodes + si2; gate -> fp32 ----------------
__global__ __launch_bounds__(256) void k_gate(
    const float* __restrict__ conv,
    const void* __restrict__ nodes,
    const void* __restrict__ W0,
    const void* __restrict__ W1,
    const void* __restrict__ W2,
    const void* __restrict__ Wg,
    float* __restrict__ out,
    const int* __restrict__ flags) {
  const int f32 = flags[0];
  __shared__ float Ws[3072];
  __shared__ float Wgs[2048];
  __shared__ float xs[NPB * DIMX];
  __shared__ float m0s[NPB][33];
  __shared__ float gs[NPB][65];
  int tid = threadIdx.x;
  for (int idx = tid; idx < 3072; idx += 256) {
    int l = idx >> 10, rem = idx & 1023;
    const void* w = (l == 0) ? W0 : ((l == 1) ? W1 : W2);
    Ws[idx] = ldf(w, rem, f32);
  }
  for (int idx = tid; idx < 2048; idx += 256) Wgs[idx] = ldf(Wg, idx, f32);
  long base = (long)blockIdx.x * NPB;
  for (int idx = tid; idx < NPB * DIMX; idx += 256) xs[idx] = conv[base * DIMX + idx];
  __syncthreads();
  int wid = tid >> 6, lane = tid & 63;
  #pragma unroll 1
  for (int t = 0; t < 4; ++t) {
    int nl = wid * 4 + t;
    long node = base + nl;
    const float* x = xs + nl * DIMX;
    float mixed[5];
    #pragma unroll
    for (int r = 0; r < 5; ++r) {
      int j = r * 64 + lane;
      if (j < DIMX) {
        float acc = 0.f;
        if (j < 32) {
          #pragma unroll
          for (int i = 0; i < 32; ++i) acc += x[i] * Ws[i * 32 + j];
        } else if (j < 128) {
          unsigned jj = j - 32; int m = jj / 3u, c = jj % 3u;
          #pragma unroll
          for (int i = 0; i < 32; ++i) acc += x[32 + 3 * i + c] * Ws[1024 + i * 32 + m];
        } else {
          unsigned jj = j - 128; int m = jj / 5u, c = jj % 5u;
          #pragma unroll
          for (int i = 0; i < 32; ++i) acc += x[128 + 5 * i + c] * Ws[2048 + i * 32 + m];
        }
        acc += ldf(nodes, node * DIMX + j, f32);
        mixed[r] = acc;
        if (j < 32) m0s[nl][j] = acc;
      }
    }
    asm volatile("" ::: "memory");
    {
      float ga = 0.f;
      #pragma unroll
      for (int m = 0; m < 32; ++m) ga += m0s[nl][m] * Wgs[m * 64 + lane];
      gs[nl][lane] = 1.f / (1.f + __expf(-ga));
    }
    asm volatile("" ::: "memory");
    #pragma unroll
    for (int r = 0; r < 5; ++r) {
      int j = r * 64 + lane;
      if (j < DIMX) {
        float v = mixed[r];
        float o;
        if (j < 32) {
          o = v / (1.f + __expf(-v));
        } else if (j < 128) {
          int m = (unsigned)(j - 32) / 3u; o = v * gs[nl][m];
        } else {
          int m = (unsigned)(j - 128) / 5u; o = v * gs[nl][32 + m];
        }
        out[node * DIMX + j] = o;
      }
    }
  }
}

extern "C" void kernel_launch(void* const* d_in, const int* in_sizes, int n_in,
                              void* d_out, int out_size, void* d_ws, size_t ws_size,
                              hipStream_t stream) {
  const void* nodes = d_in[0];
  const void* pos   = d_in[1];
  const void* W0    = d_in[2];
  const void* W1    = d_in[3];
  const void* W2    = d_in[4];
  const void* Wr1   = d_in[5];
  const void* br1   = d_in[6];
  const void* Wr2   = d_in[7];
  const void* Wg    = d_in[8];
  const int* eidx   = (const int*)d_in[10];

  char* ws = (char*)d_ws;
  int* flags          = (int*)ws;                                   // 256 B
  unsigned short* si1 = (unsigned short*)(ws + 256);                // 28.8 MB
  float* conv         = (float*)(ws + 256 + (size_t)NN * DIMX * 2); // 57.6 MB
  size_t o = 256 + (size_t)NN * DIMX * 2 + (size_t)NN * DIMX * 4;
  int* cnt   = (int*)(ws + o);            o += (size_t)NCNT * 4;    // 200 KB
  int* cur   = (int*)(ws + o);            o += (size_t)NCNT * 4;    // 200 KB
  int* src_s = (int*)(ws + o);            o += (size_t)NE * 4;      // 3.2 MB
  int* dst_s = (int*)(ws + o);                                      // 3.2 MB
  float* out = (float*)d_out;

  hipLaunchKernelGGL(k_detect, dim3(1), dim3(64), 0, stream,
                     (const unsigned short*)pos, eidx, flags);
  hipLaunchKernelGGL(k_linear1, dim3(NN / NPB), dim3(256), 0, stream,
                     nodes, W0, W1, W2, si1, flags);
  hipLaunchKernelGGL(k_zero, dim3((NN * DIMX / 4 + 255) / 256), dim3(256), 0, stream, conv);
  hipLaunchKernelGGL(k_zcnt, dim3((NCNT + 255) / 256), dim3(256), 0, stream, cnt);
  hipLaunchKernelGGL(k_count, dim3((NE + 255) / 256), dim3(256), 0, stream, eidx, cnt, flags);
  hipLaunchKernelGGL(k_scan, dim3(1), dim3(1024), 0, stream, cnt, cur);
  hipLaunchKernelGGL(k_fill, dim3((NE + 255) / 256), dim3(256), 0, stream,
                     eidx, cur, src_s, dst_s, flags);
  hipLaunchKernelGGL(k_conv, dim3(NE / 256), dim3(256), 0, stream,
                     pos, Wr1, br1, Wr2, src_s, dst_s, si1, conv, flags);
  hipLaunchKernelGGL(k_gate, dim3(NN / NPB), dim3(256), 0, stream,
                     conv, nodes, W0, W1, W2, Wg, out, flags);
}